// Round 1
// 410.243 us; speedup vs baseline: 1.0133x; 1.0133x over previous
//
#include <hip/hip_runtime.h>
#include <hip/hip_bf16.h>
#include <math.h>

#define BB 1024
#define TT 64
#define DD 256
#define PP 2048
#define HH 512

typedef __attribute__((ext_vector_type(8))) short short8;
typedef __attribute__((ext_vector_type(4))) float f32x4;

__device__ __forceinline__ float4 f4add(float4 a, float4 b) {
    return make_float4(a.x + b.x, a.y + b.y, a.z + b.z, a.w + b.w);
}

__device__ __forceinline__ void nt_store4(float* p, float4 v) {
    f32x4 t = {v.x, v.y, v.z, v.w};
    __builtin_nontemporal_store(t, (f32x4*)p);
}

__device__ __forceinline__ void nt_store1(float* p, float v) {
    __builtin_nontemporal_store(v, p);
}

// ---------------- block reduction helpers (256 threads) ----------------
__device__ __forceinline__ float blk_reduce(float v, float* sm) {
    int tid = threadIdx.x;
    #pragma unroll
    for (int o = 32; o > 0; o >>= 1) v += __shfl_down(v, o, 64);
    if ((tid & 63) == 0) sm[tid >> 6] = v;
    __syncthreads();
    float r = sm[0] + sm[1] + sm[2] + sm[3];
    __syncthreads();
    return r;
}

// two values in one barrier round
__device__ __forceinline__ float2 blk_reduce2(float a, float b, float* sm) {
    int tid = threadIdx.x;
    #pragma unroll
    for (int o = 32; o > 0; o >>= 1) {
        a += __shfl_down(a, o, 64);
        b += __shfl_down(b, o, 64);
    }
    if ((tid & 63) == 0) { sm[(tid >> 6) * 2] = a; sm[(tid >> 6) * 2 + 1] = b; }
    __syncthreads();
    float ra = sm[0] + sm[2] + sm[4] + sm[6];
    float rb = sm[1] + sm[3] + sm[5] + sm[7];
    __syncthreads();
    return make_float2(ra, rb);
}

// ---------------- batched T-mean for one [64,256] row ----------------
// All 16 float4 loads issued before any consumption; tree sum; ONE barrier.
// Returns column mean for column = tid.
__device__ __forceinline__ float row_mean_batch(const float* __restrict__ base,
                                                float* __restrict__ smr) {
    int tid = threadIdx.x;
    int c4 = tid & 63;      // column group (4 cols)
    int t0 = tid >> 6;      // phase 0..3
    const float* p = base + t0 * DD + (c4 << 2);
    float4 v[16];
    #pragma unroll
    for (int i = 0; i < 16; ++i)
        v[i] = *(const float4*)(p + (i << 2) * DD);   // t = t0 + 4*i
    #pragma unroll
    for (int i = 0; i < 8; ++i) v[i] = f4add(v[i], v[i + 8]);
    #pragma unroll
    for (int i = 0; i < 4; ++i) v[i] = f4add(v[i], v[i + 4]);
    float4 s = f4add(f4add(v[0], v[1]), f4add(v[2], v[3]));
    *(float4*)&smr[t0 * 256 + (c4 << 2)] = s;
    __syncthreads();
    return (smr[tid] + smr[256 + tid] + smr[512 + tid] + smr[768 + tid]) * (1.f / TT);
}

// ================ K1: prep — reductions + weight cvt, role by blockIdx ===========
__global__ void prep_k(const float* __restrict__ cf, const float* __restrict__ proto,
                       const float* __restrict__ dd_w1, const float* __restrict__ dd_w2,
                       const float* __restrict__ cal_w1, const float* __restrict__ cal_w2,
                       const float* __restrict__ cal_w3,
                       float* __restrict__ ffm, float* __restrict__ fn,
                       float* __restrict__ pn, float* __restrict__ pc,
                       __hip_bfloat16* __restrict__ ffb, __hip_bfloat16* __restrict__ pcb,
                       __hip_bfloat16* __restrict__ w1cat, __hip_bfloat16* __restrict__ w2dd,
                       __hip_bfloat16* __restrict__ w2cal, __hip_bfloat16* __restrict__ w3cal) {
    __shared__ float smr[1024];
    __shared__ float sm[4];
    int b = blockIdx.x, tid = threadIdx.x;
    if (b < 1024) {                       // reduce current_feat row b
        float m = row_mean_batch(cf + (size_t)b * TT * DD, smr);
        ffm[(size_t)b * DD + tid] = m;                      // fp32 for gmean (no atomics)
        ffb[(size_t)b * DD + tid] = __float2bfloat16(m);
        float q = m * m;
        #pragma unroll
        for (int o = 32; o > 0; o >>= 1) q += __shfl_down(q, o, 64);
        if ((tid & 63) == 0) sm[tid >> 6] = q;
        __syncthreads();
        if (tid == 0) fn[b] = fmaxf(sqrtf(sm[0] + sm[1] + sm[2] + sm[3]), 1e-8f);
    } else if (b < 3072) {                // reduce prototype row
        int r = b - 1024;
        float m = row_mean_batch(proto + (size_t)r * TT * DD, smr);
        pc[(size_t)r * DD + tid] = m;
        pcb[(size_t)r * DD + tid] = __float2bfloat16(m);
        float q = m * m;
        #pragma unroll
        for (int o = 32; o > 0; o >>= 1) q += __shfl_down(q, o, 64);
        if ((tid & 63) == 0) sm[tid >> 6] = q;
        __syncthreads();
        if (tid == 0) pn[r] = fmaxf(sqrtf(sm[0] + sm[1] + sm[2] + sm[3]), 1e-8f);
    } else {                              // weight convert+transpose
        int idx = (b - 3072) * 256 + tid;
        if (idx < 262144) {               // w1cat: dd_w1 | cal_w1, K=256 N=512 each
            int half = idx >> 17;         // 0: dd, 1: cal
            int i = idx & 131071;
            int n = i & 511, k = i >> 9;
            const float* src = half ? cal_w1 : dd_w1;
            w1cat[(size_t)(half * 512 + n) * 256 + k] = __float2bfloat16(src[(size_t)k * 512 + n]);
        } else if (idx < 393216) {        // w2dd: K=512 N=256
            int i = idx - 262144;
            int n = i & 255, k = i >> 8;
            w2dd[(size_t)n * 512 + k] = __float2bfloat16(dd_w2[(size_t)k * 256 + n]);
        } else if (idx < 655360) {        // w2cal: K=512 N=512
            int i = idx - 393216;
            int n = i & 511, k = i >> 9;
            w2cal[(size_t)n * 512 + k] = __float2bfloat16(cal_w2[(size_t)k * 512 + n]);
        } else {                          // w3cal: K=512 N=256
            int i = idx - 655360;
            int n = i & 255, k = i >> 8;
            w3cal[(size_t)n * 512 + k] = __float2bfloat16(cal_w3[(size_t)k * 256 + n]);
        }
    }
}

// ================ K2: sim MFMA + addvec, role by blockIdx =====================
__global__ void sim_addvec_k(const __hip_bfloat16* __restrict__ A,
                             const __hip_bfloat16* __restrict__ Bt,
                             const float* __restrict__ fn, const float* __restrict__ pn,
                             const float* __restrict__ ffm,
                             const float* __restrict__ dd_w1, const float* __restrict__ dd_b1,
                             float* __restrict__ drift, float* __restrict__ colsum,
                             float* __restrict__ addvec) {
    if (blockIdx.x >= 512) {              // addvec role: 2 blocks x 256 j's
        __shared__ float gmk[256];
        int tid = threadIdx.x;
        const float* f = ffm + tid;
        float a0 = 0.f, a1 = 0.f, a2 = 0.f, a3 = 0.f, a4 = 0.f, a5 = 0.f, a6 = 0.f, a7 = 0.f;
        #pragma unroll 4
        for (int b = 0; b < 1024; b += 8) {
            a0 += f[(b + 0) << 8]; a1 += f[(b + 1) << 8];
            a2 += f[(b + 2) << 8]; a3 += f[(b + 3) << 8];
            a4 += f[(b + 4) << 8]; a5 += f[(b + 5) << 8];
            a6 += f[(b + 6) << 8]; a7 += f[(b + 7) << 8];
        }
        gmk[tid] = (((a0 + a1) + (a2 + a3)) + ((a4 + a5) + (a6 + a7))) * (1.f / BB);
        __syncthreads();
        int j = (blockIdx.x - 512) * 256 + tid;
        float s = dd_b1[j];
        #pragma unroll 8
        for (int k = 0; k < 256; ++k) s = fmaf(gmk[k], dd_w1[(size_t)(256 + k) * 512 + j], s);
        addvec[j] = s;
        return;
    }
    int wid = (blockIdx.x << 2) + (threadIdx.x >> 6);   // 0..2047
    int lane = threadIdx.x & 63;
    int mw = wid >> 6, nw = wid & 63;
    int m0 = mw << 5, n0 = nw << 5;
    int lr = lane & 15, quad = lane >> 4;
    const __hip_bfloat16* pa0 = A + (size_t)(m0 + lr) * DD + quad * 8;
    const __hip_bfloat16* pa1 = pa0 + 16 * DD;
    const __hip_bfloat16* pb0 = Bt + (size_t)(n0 + lr) * DD + quad * 8;
    const __hip_bfloat16* pb1 = pb0 + 16 * DD;
    f32x4 acc00 = {0,0,0,0}, acc01 = {0,0,0,0}, acc10 = {0,0,0,0}, acc11 = {0,0,0,0};
    #pragma unroll
    for (int k = 0; k < DD; k += 32) {
        short8 a0 = *(const short8*)(pa0 + k);
        short8 a1 = *(const short8*)(pa1 + k);
        short8 b0 = *(const short8*)(pb0 + k);
        short8 b1 = *(const short8*)(pb1 + k);
        acc00 = __builtin_amdgcn_mfma_f32_16x16x32_bf16(a0, b0, acc00, 0, 0, 0);
        acc01 = __builtin_amdgcn_mfma_f32_16x16x32_bf16(a0, b1, acc01, 0, 0, 0);
        acc10 = __builtin_amdgcn_mfma_f32_16x16x32_bf16(a1, b0, acc10, 0, 0, 0);
        acc11 = __builtin_amdgcn_mfma_f32_16x16x32_bf16(a1, b1, acc11, 0, 0, 0);
    }
    int col0 = n0 + lr, col1 = col0 + 16;
    float ip0 = 1.f / pn[col0], ip1 = 1.f / pn[col1];
    float cs0 = 0.f, cs1 = 0.f;
    #pragma unroll
    for (int r = 0; r < 4; ++r) {
        int row0 = m0 + quad * 4 + r;
        int row1 = row0 + 16;
        float if0 = 1.f / fn[row0];
        float if1 = 1.f / fn[row1];
        float d00 = 1.f - acc00[r] * if0 * ip0;
        float d01 = 1.f - acc01[r] * if0 * ip1;
        float d10 = 1.f - acc10[r] * if1 * ip0;
        float d11 = 1.f - acc11[r] * if1 * ip1;
        nt_store1(&drift[(size_t)row0 * PP + col0], d00);
        nt_store1(&drift[(size_t)row0 * PP + col1], d01);
        nt_store1(&drift[(size_t)row1 * PP + col0], d10);
        nt_store1(&drift[(size_t)row1 * PP + col1], d11);
        cs0 += d00 + d10;
        cs1 += d01 + d11;
    }
    cs0 += __shfl_xor(cs0, 16, 64); cs0 += __shfl_xor(cs0, 32, 64);
    cs1 += __shfl_xor(cs1, 16, 64); cs1 += __shfl_xor(cs1, 32, 64);
    if (quad == 0) {
        atomicAdd(&colsum[col0], cs0);
        atomicAdd(&colsum[col1], cs1);
    }
}

// ================ 32x32 MFMA tile device function ============================
template <int K, int OUT_BF16, int RELU>
__device__ __forceinline__ void gemm_tile(const __hip_bfloat16* __restrict__ A,
                                          const __hip_bfloat16* __restrict__ Bt,
                                          const float* __restrict__ bias0,
                                          const float* __restrict__ bias1, int split,
                                          void* __restrict__ Cout, int N, int lognt,
                                          int wid, int lane) {
    int mw = wid >> lognt, nw = wid & ((1 << lognt) - 1);
    int m0 = mw << 5, n0 = nw << 5;
    int lr = lane & 15, quad = lane >> 4;
    const __hip_bfloat16* pa0 = A + (size_t)(m0 + lr) * K + quad * 8;
    const __hip_bfloat16* pa1 = pa0 + 16 * K;
    const __hip_bfloat16* pb0 = Bt + (size_t)(n0 + lr) * K + quad * 8;
    const __hip_bfloat16* pb1 = pb0 + 16 * K;
    f32x4 acc00 = {0,0,0,0}, acc01 = {0,0,0,0}, acc10 = {0,0,0,0}, acc11 = {0,0,0,0};
    #pragma unroll
    for (int k = 0; k < K; k += 32) {
        short8 a0 = *(const short8*)(pa0 + k);
        short8 a1 = *(const short8*)(pa1 + k);
        short8 b0 = *(const short8*)(pb0 + k);
        short8 b1 = *(const short8*)(pb1 + k);
        acc00 = __builtin_amdgcn_mfma_f32_16x16x32_bf16(a0, b0, acc00, 0, 0, 0);
        acc01 = __builtin_amdgcn_mfma_f32_16x16x32_bf16(a0, b1, acc01, 0, 0, 0);
        acc10 = __builtin_amdgcn_mfma_f32_16x16x32_bf16(a1, b0, acc10, 0, 0, 0);
        acc11 = __builtin_amdgcn_mfma_f32_16x16x32_bf16(a1, b1, acc11, 0, 0, 0);
    }
    int col0 = n0 + lr, col1 = col0 + 16;
    float bi0 = (col0 < split) ? bias0[col0] : bias1[col0 - split];
    float bi1 = (col1 < split) ? bias0[col1] : bias1[col1 - split];
    #pragma unroll
    for (int r = 0; r < 4; ++r) {
        int row0 = m0 + quad * 4 + r;
        int row1 = row0 + 16;
        float v00 = acc00[r] + bi0, v01 = acc01[r] + bi1;
        float v10 = acc10[r] + bi0, v11 = acc11[r] + bi1;
        if (RELU) {
            v00 = fmaxf(v00, 0.f); v01 = fmaxf(v01, 0.f);
            v10 = fmaxf(v10, 0.f); v11 = fmaxf(v11, 0.f);
        }
        if (OUT_BF16) {
            __hip_bfloat16* C = (__hip_bfloat16*)Cout;
            C[(size_t)row0 * N + col0] = __float2bfloat16(v00);
            C[(size_t)row0 * N + col1] = __float2bfloat16(v01);
            C[(size_t)row1 * N + col0] = __float2bfloat16(v10);
            C[(size_t)row1 * N + col1] = __float2bfloat16(v11);
        } else {
            float* C = (float*)Cout;
            C[(size_t)row0 * N + col0] = v00;
            C[(size_t)row0 * N + col1] = v01;
            C[(size_t)row1 * N + col0] = v10;
            C[(size_t)row1 * N + col1] = v11;
        }
    }
}

// ================ K3: layer-1 GEMM for both MLPs (N=1024 concat) ==============
__global__ void gemm1_k(const __hip_bfloat16* __restrict__ pcb,
                        const __hip_bfloat16* __restrict__ w1cat,
                        const float* __restrict__ addvec, const float* __restrict__ cal_b1,
                        float* __restrict__ buf1) {
    int wid = (blockIdx.x << 2) + (threadIdx.x >> 6);
    gemm_tile<256, 0, 0>(pcb, w1cat, addvec, cal_b1, 512, buf1, 1024, 5,
                         wid, threadIdx.x & 63);
}

// ================ K4: dual layernorm+relu (512 | 512), fp32 -> bf16 ===========
__global__ void ln2_k(const float* __restrict__ X,
                      __hip_bfloat16* __restrict__ Ydd, __hip_bfloat16* __restrict__ Ycal,
                      const float* __restrict__ gdd, const float* __restrict__ bedd,
                      const float* __restrict__ gcal, const float* __restrict__ becal) {
    __shared__ float sm[8];
    int r = blockIdx.x, tid = threadIdx.x;
    const float* row = X + (size_t)r * 1024;
    // dd half (cols 0..511) — one fused sum/sumsq reduction
    {
        float x0 = row[tid], x1 = row[tid + 256];
        float2 t = blk_reduce2(x0 + x1, x0 * x0 + x1 * x1, sm);
        float mu = t.x * (1.f / HH);
        float var = fmaxf(t.y * (1.f / HH) - mu * mu, 0.f);
        float rs = rsqrtf(var + 1e-5f);
        float d0 = x0 - mu, d1 = x1 - mu;
        __hip_bfloat16* y = Ydd + (size_t)r * HH;
        y[tid]       = __float2bfloat16(fmaxf(d0 * rs * gdd[tid] + bedd[tid], 0.f));
        y[tid + 256] = __float2bfloat16(fmaxf(d1 * rs * gdd[tid + 256] + bedd[tid + 256], 0.f));
    }
    // cal half (cols 512..1023)
    {
        float x0 = row[512 + tid], x1 = row[768 + tid];
        float2 t = blk_reduce2(x0 + x1, x0 * x0 + x1 * x1, sm);
        float mu = t.x * (1.f / HH);
        float var = fmaxf(t.y * (1.f / HH) - mu * mu, 0.f);
        float rs = rsqrtf(var + 1e-5f);
        float d0 = x0 - mu, d1 = x1 - mu;
        __hip_bfloat16* y = Ycal + (size_t)r * HH;
        y[tid]       = __float2bfloat16(fmaxf(d0 * rs * gcal[tid] + becal[tid], 0.f));
        y[tid + 256] = __float2bfloat16(fmaxf(d1 * rs * gcal[tid + 256] + becal[tid + 256], 0.f));
    }
}

// ================ K5: dd2 + cal2 GEMMs, role by blockIdx ======================
__global__ void gemm2_k(const __hip_bfloat16* __restrict__ act_dd,
                        const __hip_bfloat16* __restrict__ act_cal,
                        const __hip_bfloat16* __restrict__ w2dd,
                        const __hip_bfloat16* __restrict__ w2cal,
                        const float* __restrict__ dd_b2, const float* __restrict__ cal_b2,
                        __hip_bfloat16* __restrict__ act2b, __hip_bfloat16* __restrict__ act3b) {
    int lane = threadIdx.x & 63;
    if (blockIdx.x < 128) {   // dd2: [2048,512]@[512,256] -> act2b
        int wid = (blockIdx.x << 2) + (threadIdx.x >> 6);
        gemm_tile<512, 1, 1>(act_dd, w2dd, dd_b2, dd_b2, 1 << 30, act2b, 256, 3, wid, lane);
    } else {                  // cal2: [2048,512]@[512,512] -> act3b
        int wid = ((blockIdx.x - 128) << 2) + (threadIdx.x >> 6);
        gemm_tile<512, 1, 1>(act_cal, w2cal, cal_b2, cal_b2, 1 << 30, act3b, 512, 4, wid, lane);
    }
}

// ================ K6: cal3 GEMM + conf/sigmoid/is_drifted =====================
__global__ void gemm3_conf_k(const __hip_bfloat16* __restrict__ act3b,
                             const __hip_bfloat16* __restrict__ w3cal,
                             const float* __restrict__ cal_b3,
                             const __hip_bfloat16* __restrict__ act2b,
                             const float* __restrict__ dd_w3, const float* __restrict__ dd_b3,
                             const float* __restrict__ colsum,
                             float* __restrict__ delta, float* __restrict__ strength,
                             float* __restrict__ out_is) {
    if (blockIdx.x < 128) {   // cal3: [2048,512]@[512,256] -> delta fp32
        int wid = (blockIdx.x << 2) + (threadIdx.x >> 6);
        gemm_tile<512, 0, 0>(act3b, w3cal, cal_b3, cal_b3, 1 << 30, delta, 256, 3,
                             wid, threadIdx.x & 63);
        return;
    }
    // conf role: one wave per p, blocks 128..639
    int p = ((blockIdx.x - 128) << 2) + (threadIdx.x >> 6);   // 0..2047
    int lane = threadIdx.x & 63;
    const __hip_bfloat16* row = act2b + (size_t)p * 256 + lane * 4;
    float s = 0.f;
    #pragma unroll
    for (int j = 0; j < 4; ++j)
        s += __bfloat162float(row[j]) * dd_w3[lane * 4 + j];
    #pragma unroll
    for (int o = 32; o > 0; o >>= 1) s += __shfl_down(s, o, 64);
    if (lane == 0) {
        float conf = 1.f / (1.f + expf(-(s + dd_b3[0])));
        strength[p] = fminf(fmaxf(0.1f * conf, 0.f), 0.5f);
        out_is[p] = (colsum[p] * (1.f / BB) > 0.3f) ? 1.f : 0.f;
    }
}

// ================ K7: write calibrated [P,T,D], nontemporal float4 ============
__global__ void finalize_k(const float* __restrict__ pc, const float* __restrict__ delta,
                           const float* __restrict__ strength, const float* __restrict__ colsum,
                           const float* __restrict__ proto, float* __restrict__ out) {
    int p = blockIdx.x;
    int d4 = (threadIdx.x & 63) << 2;
    int t0 = threadIdx.x >> 6;
    bool dr = colsum[p] * (1.f / BB) > 0.3f;
    float* o = out + (size_t)p * TT * DD;
    if (dr) {
        float s = strength[p];
        float4 pcv = *(const float4*)(pc + (size_t)p * DD + d4);
        float4 dv  = *(const float4*)(delta + (size_t)p * DD + d4);
        float4 nc = make_float4(fmaf(s, dv.x, pcv.x), fmaf(s, dv.y, pcv.y),
                                fmaf(s, dv.z, pcv.z), fmaf(s, dv.w, pcv.w));
        #pragma unroll
        for (int t = t0; t < TT; t += 4)
            nt_store4(o + t * DD + d4, nc);
    } else {
        const float* pr = proto + (size_t)p * TT * DD;
        #pragma unroll
        for (int t = t0; t < TT; t += 4)
            nt_store4(o + t * DD + d4, *(const float4*)(pr + t * DD + d4));
    }
}

extern "C" void kernel_launch(void* const* d_in, const int* in_sizes, int n_in,
                              void* d_out, int out_size, void* d_ws, size_t ws_size,
                              hipStream_t stream) {
    const float* cf     = (const float*)d_in[0];
    const float* proto  = (const float*)d_in[1];
    const float* dd_w1  = (const float*)d_in[2];
    const float* dd_b1  = (const float*)d_in[3];
    const float* dd_g1  = (const float*)d_in[4];
    const float* dd_be1 = (const float*)d_in[5];
    const float* dd_w2  = (const float*)d_in[6];
    const float* dd_b2  = (const float*)d_in[7];
    const float* dd_w3  = (const float*)d_in[8];
    const float* dd_b3  = (const float*)d_in[9];
    const float* cal_w1 = (const float*)d_in[10];
    const float* cal_b1 = (const float*)d_in[11];
    const float* cal_g1 = (const float*)d_in[12];
    const float* cal_be1= (const float*)d_in[13];
    const float* cal_w2 = (const float*)d_in[14];
    const float* cal_b2 = (const float*)d_in[15];
    const float* cal_w3 = (const float*)d_in[16];
    const float* cal_b3 = (const float*)d_in[17];

    float* out_cal   = (float*)d_out;
    float* out_drift = out_cal + (size_t)PP * TT * DD;
    float* out_is    = out_drift + (size_t)BB * PP;

    float* w = (float*)d_ws;
    float* colsum   = w;               // 2048 (memset)
    float* addvec   = w + 4096;        // 512
    float* fn       = w + 4608;        // 1024
    float* pn       = w + 5632;        // 2048
    float* strength = w + 7680;        // 2048
    float* pc       = w + 9728;        // 2048*256
    float* buf1     = w + 534016;      // 2048*1024
    float* ffm      = buf1;            // 1024*256 fp32 — consumed by sim's addvec
                                       // role BEFORE gemm1 overwrites buf1
    float* delta    = w + 2631168;     // 2048*256
    __hip_bfloat16* bb = (__hip_bfloat16*)(w + 3155456);
    __hip_bfloat16* ffb     = bb;                 // 1024*256
    __hip_bfloat16* pcb     = bb + 262144;        // 2048*256
    __hip_bfloat16* w1cat   = bb + 786432;        // 1024*256
    __hip_bfloat16* w2dd    = bb + 1048576;       // 256*512
    __hip_bfloat16* w2cal   = bb + 1179648;       // 512*512
    __hip_bfloat16* w3cal   = bb + 1441792;       // 256*512
    __hip_bfloat16* act_dd  = bb + 1572864;       // 2048*512
    __hip_bfloat16* act_cal = bb + 2621440;       // 2048*512
    __hip_bfloat16* act2b   = bb + 3670016;       // 2048*256
    __hip_bfloat16* act3b   = bb + 4194304;       // 2048*512

    hipMemsetAsync(colsum, 0, 2048 * sizeof(float), stream);  // colsum only

    prep_k<<<6144, 256, 0, stream>>>(cf, proto, dd_w1, dd_w2, cal_w1, cal_w2, cal_w3,
                                     ffm, fn, pn, pc, ffb, pcb,
                                     w1cat, w2dd, w2cal, w3cal);
    sim_addvec_k<<<514, 256, 0, stream>>>(ffb, pcb, fn, pn, ffm, dd_w1, dd_b1,
                                          out_drift, colsum, addvec);
    gemm1_k<<<512, 256, 0, stream>>>(pcb, w1cat, addvec, cal_b1, buf1);
    ln2_k<<<PP, 256, 0, stream>>>(buf1, act_dd, act_cal, dd_g1, dd_be1, cal_g1, cal_be1);
    gemm2_k<<<384, 256, 0, stream>>>(act_dd, act_cal, w2dd, w2cal, dd_b2, cal_b2,
                                     act2b, act3b);
    gemm3_conf_k<<<640, 256, 0, stream>>>(act3b, w3cal, cal_b3, act2b, dd_w3, dd_b3,
                                          colsum, delta, strength, out_is);
    finalize_k<<<PP, 256, 0, stream>>>(pc, delta, strength, colsum, proto, out_cal);
}